// Round 6
// baseline (358.073 us; speedup 1.0000x reference)
//
#include <hip/hip_runtime.h>

// ---------------------------------------------------------------------------
// EncoderLayer, MI355X gfx950. fp32 I/O, bf16 MFMA internally.
// r14: gemm256 v2 — BK=64, DOUBLE-buffered LDS (2 x [A 256x64 | B 256x64]
//      = 128KB), staging issued at tile TOP (8 async_cp16/thread) so the
//      end-of-tile vmcnt(0)+barrier is nearly free (compute wall ~2500cyc
//      >> L2 latency); boundaries per block halved (32 -> 16 @ K=1024).
//      Swizzle for 128B row stride: chunk cb = g ^ (row&7) on BOTH the
//      global_load_lds source and the ds_read side (2-way residual = free).
//      attn kept at r13 (71.7us, 0 conflicts — chain-bound, at floor).
// MFMA 16x16x32 bf16 layouts (m89/m91 verified):
//   A: lane holds A[m=lane&15][k=quad*8+j]; B: Bt[n=lane&15][k=quad*8+j]
//   C/D: reg r -> row=quad*4+r, col=lane&15
// Workspace (MB): 0-6 wqkvT | 6-8 woT | 8-16 w1T | 16-24 w2T | 24-32 ln |
//   32-48 qkb | 48-56 vbT | 56-64 ao | 64-80 x2 | 80-96 partials hi
// ---------------------------------------------------------------------------

typedef __attribute__((ext_vector_type(8))) unsigned short u16x8;
typedef __attribute__((ext_vector_type(4))) unsigned short u16x4;
typedef __attribute__((ext_vector_type(8))) __bf16 bf16x8;
typedef __attribute__((ext_vector_type(4))) float f32x4;
typedef __attribute__((ext_vector_type(4))) unsigned int u32x4;

#define C_SCALE 0.1803368801111f   // log2(e)/8 — folded into wk/bk

static __device__ __forceinline__ unsigned short f2b(float f) {
    return __builtin_bit_cast(unsigned short, (__bf16)f);
}
static __device__ __forceinline__ float b2f(unsigned short h) {
    unsigned u = ((unsigned)h) << 16;
    float f;
    __builtin_memcpy(&f, &u, 4);
    return f;
}

static __device__ __forceinline__ void async_cp16(
    const unsigned short* g, unsigned short* l)
{
    __builtin_amdgcn_global_load_lds(
        (const __attribute__((address_space(1))) unsigned int*)g,
        (__attribute__((address_space(3))) unsigned int*)l,
        16, 0, 0);
}

// ---------------------------------------------------------------------------
// All six weight transposes (fp32 -> bf16, [R][C] -> [C][R]) in one launch.
// ---------------------------------------------------------------------------
__global__ __launch_bounds__(256) void transpose_all_k(
    const float* __restrict__ wq, const float* __restrict__ wk,
    const float* __restrict__ wv, const float* __restrict__ wo,
    const float* __restrict__ w1, const float* __restrict__ w2,
    unsigned short* __restrict__ wqkvT, unsigned short* __restrict__ woT,
    unsigned short* __restrict__ w1T, unsigned short* __restrict__ w2T)
{
    __shared__ unsigned short tile[32][33];
    const int ti = blockIdx.x;
    const float* in;
    unsigned short* out;
    int R, C, bi, bj;
    float sc = 1.0f;
    if (ti < 4096) {
        R = 1024; C = 1024;
        bi = (ti & 1023) >> 5; bj = ti & 31;
        int z = ti >> 10;
        in = (z == 0) ? wq : (z == 1) ? wk : (z == 2) ? wv : wo;
        out = (z < 3) ? wqkvT + (size_t)z * 1024 * 1024 : woT;
        if (z == 1) sc = C_SCALE;
    } else if (ti < 8192) {
        R = 1024; C = 4096;
        int l = ti - 4096;
        bi = l >> 7; bj = l & 127;
        in = w1; out = w1T;
    } else {
        R = 4096; C = 1024;
        int l = ti - 8192;
        bi = l >> 5; bj = l & 31;
        in = w2; out = w2T;
    }
    const int tx = threadIdx.x & 31, ty = threadIdx.x >> 5;
#pragma unroll
    for (int rr = 0; rr < 4; ++rr) {
        int r = ty + rr * 8;
        tile[r][tx] = f2b(in[(size_t)(bi * 32 + r) * C + bj * 32 + tx] * sc);
    }
    __syncthreads();
#pragma unroll
    for (int rr = 0; rr < 4; ++rr) {
        int r = ty + rr * 8;
        out[(size_t)(bj * 32 + r) * R + bi * 32 + tx] = tile[tx][r];
    }
}

__global__ __launch_bounds__(256) void concat3_k(
    const float* __restrict__ a, const float* __restrict__ b,
    const float* __restrict__ c, float* __restrict__ o)
{
    int t = blockIdx.x * 256 + threadIdx.x;
    float v = (t < 1024) ? a[t]
            : ((t < 2048) ? b[t - 1024] * C_SCALE : c[t - 2048]);
    o[t] = v;
}

// ---------------------------------------------------------------------------
__global__ __launch_bounds__(256) void ln_kernel(
    const float* __restrict__ x, const float* __restrict__ g,
    const float* __restrict__ be, unsigned short* __restrict__ o)
{
    const int row = blockIdx.x;
    const int t = threadIdx.x;
    const float* xr = x + (size_t)row * 1024;
    float4 v4 = *reinterpret_cast<const float4*>(&xr[t * 4]);
    float f[4] = {v4.x, v4.y, v4.z, v4.w};
    float s = f[0] + f[1] + f[2] + f[3];
    float ss = f[0] * f[0] + f[1] * f[1] + f[2] * f[2] + f[3] * f[3];
#pragma unroll
    for (int d = 1; d < 64; d <<= 1) {
        s += __shfl_xor(s, d);
        ss += __shfl_xor(ss, d);
    }
    __shared__ float sb[4], ssb[4];
    const int wave = t >> 6;
    if ((t & 63) == 0) { sb[wave] = s; ssb[wave] = ss; }
    __syncthreads();
    s = sb[0] + sb[1] + sb[2] + sb[3];
    ss = ssb[0] + ssb[1] + ssb[2] + ssb[3];
    const float mu = s * (1.0f / 1024.0f);
    const float var = ss * (1.0f / 1024.0f) - mu * mu;
    const float rs = rsqrtf(var + 1e-5f);
    u16x4 r4;
#pragma unroll
    for (int j = 0; j < 4; ++j)
        r4[j] = f2b((f[j] - mu) * rs * g[t * 4 + j] + be[t * 4 + j]);
    *reinterpret_cast<u16x4*>(&o[(size_t)row * 1024 + t * 4]) = r4;
}

// ---------------------------------------------------------------------------
// Fused: x2 = sum(4 bf16 partials) + bias + x;  ln = LayerNorm(x2; g, be)
// ---------------------------------------------------------------------------
__global__ __launch_bounds__(256) void reduce_ln_kernel(
    const unsigned short* __restrict__ pa, const unsigned short* __restrict__ pb,
    const float* __restrict__ bias, const float* __restrict__ x,
    const float* __restrict__ g, const float* __restrict__ be,
    float* __restrict__ x2, unsigned short* __restrict__ o)
{
    const int row = blockIdx.x;
    const int t = threadIdx.x;
    const size_t base = (size_t)row * 1024 + t * 4;
    float4 x4 = *reinterpret_cast<const float4*>(&x[base]);
    float4 bb = *reinterpret_cast<const float4*>(&bias[t * 4]);
    float f[4] = {x4.x + bb.x, x4.y + bb.y, x4.z + bb.z, x4.w + bb.w};
#pragma unroll
    for (int z = 0; z < 2; ++z) {
        u16x4 va = *reinterpret_cast<const u16x4*>(&pa[(size_t)z * 4096 * 1024 + base]);
        u16x4 vb = *reinterpret_cast<const u16x4*>(&pb[(size_t)z * 4096 * 1024 + base]);
#pragma unroll
        for (int j = 0; j < 4; ++j) f[j] += b2f(va[j]) + b2f(vb[j]);
    }
    *reinterpret_cast<float4*>(&x2[base]) = {f[0], f[1], f[2], f[3]};
    float s = f[0] + f[1] + f[2] + f[3];
    float ss = f[0] * f[0] + f[1] * f[1] + f[2] * f[2] + f[3] * f[3];
#pragma unroll
    for (int d = 1; d < 64; d <<= 1) {
        s += __shfl_xor(s, d);
        ss += __shfl_xor(ss, d);
    }
    __shared__ float sb[4], ssb[4];
    const int wave = t >> 6;
    if ((t & 63) == 0) { sb[wave] = s; ssb[wave] = ss; }
    __syncthreads();
    s = sb[0] + sb[1] + sb[2] + sb[3];
    ss = ssb[0] + ssb[1] + ssb[2] + ssb[3];
    const float mu = s * (1.0f / 1024.0f);
    const float var = ss * (1.0f / 1024.0f) - mu * mu;
    const float rs = rsqrtf(var + 1e-5f);
    u16x4 r4;
#pragma unroll
    for (int j = 0; j < 4; ++j)
        r4[j] = f2b((f[j] - mu) * rs * g[t * 4 + j] + be[t * 4 + j]);
    *reinterpret_cast<u16x4*>(&o[base]) = r4;
}

// ---------------------------------------------------------------------------
// Fused final: out = sum(4 bf16 partials) + bias + x2
// ---------------------------------------------------------------------------
__global__ __launch_bounds__(256) void reduce_out4_k(
    const unsigned short* __restrict__ pa, const unsigned short* __restrict__ pb,
    const float* __restrict__ bias, const float* __restrict__ x2,
    float* __restrict__ out)
{
    const size_t i4 = ((size_t)blockIdx.x * 256 + threadIdx.x) * 4;
    float4 x4 = *reinterpret_cast<const float4*>(&x2[i4]);
    float4 bb = *reinterpret_cast<const float4*>(&bias[i4 & 1023]);
    float a0 = x4.x + bb.x, a1 = x4.y + bb.y, a2 = x4.z + bb.z, a3 = x4.w + bb.w;
#pragma unroll
    for (int z = 0; z < 2; ++z) {
        u16x4 va = *reinterpret_cast<const u16x4*>(&pa[(size_t)z * 4096 * 1024 + i4]);
        u16x4 vb = *reinterpret_cast<const u16x4*>(&pb[(size_t)z * 4096 * 1024 + i4]);
        a0 += b2f(va[0]) + b2f(vb[0]);
        a1 += b2f(va[1]) + b2f(vb[1]);
        a2 += b2f(va[2]) + b2f(vb[2]);
        a3 += b2f(va[3]) + b2f(vb[3]);
    }
    *reinterpret_cast<float4*>(&out[i4]) = {a0, a1, a2, a3};
}

// ---------------------------------------------------------------------------
// gemm256 v2: C[M][.] = A[M][lda] @ Bt[.][ldb]^T (+bias)(+ReLU)
// BM=BN=256, BK=64, 512 threads (8 waves: wm=w>>2, wn=w&3), per-wave 128x64.
// DOUBLE-buffered LDS (2 x [A 256x64 | B 256x64] bf16 = 128KB). Staging (8
// async_cp16/thread) issued at tile TOP into buf^1; boundary = vmcnt(0) +
// ONE barrier per 64-K tile (loads had the whole tile to land -> cheap).
// Swizzle (both sides): chunk cb = g ^ (row & 7)  [128B row = 8 x 16B chunks].
// MODE 0: bf16 row-major (+ReLU); 2: fused QKV epilogue; 5: partial slices.
// ---------------------------------------------------------------------------
template<int MODE, int RELU>
__global__ __launch_bounds__(512, 1) void gemm256(
    const unsigned short* __restrict__ A, int lda,
    const unsigned short* __restrict__ Bt, int ldb,
    const float* __restrict__ bias,
    void* __restrict__ Cv, void* __restrict__ Cv2, int N, int Kloop)
{
    __shared__ unsigned short lds[65536];   // 128 KB: [2][A 16384 | B 16384]
    const int t = threadIdx.x;
    const int wave = t >> 6, lane = t & 63;
    const int quad = lane >> 4, l16 = lane & 15;
    const int wm = wave >> 2, wn = wave & 3;
    const int m0 = blockIdx.y * 256;
    const int n0 = blockIdx.x * 256;
    const int k0 = blockIdx.z * Kloop;
    const int NT = Kloop >> 6;

    // staging pointers: chunk c = t + j*512 -> row c>>3, LDS cb = c&7,
    // global chunk = cb ^ (row&7) (inverse swizzle on the source)
    const unsigned short* Ap[4];
    const unsigned short* Bp[4];
#pragma unroll
    for (int j = 0; j < 4; ++j) {
        const int c = t + j * 512;
        const int row = c >> 3;
        const int gcb = (c & 7) ^ (row & 7);
        Ap[j] = &A[(size_t)(m0 + row) * lda + k0 + gcb * 8];
        Bp[j] = &Bt[(size_t)(n0 + row) * ldb + k0 + gcb * 8];
    }
    auto GSTAGE = [&](int buf) {
        unsigned short* La = &lds[buf * 32768];
        unsigned short* LbB = La + 16384;
#pragma unroll
        for (int j = 0; j < 4; ++j) {
            async_cp16(Ap[j], &La[(t + j * 512) * 8]);
            async_cp16(Bp[j], &LbB[(t + j * 512) * 8]);
            Ap[j] += 64;
            Bp[j] += 64;
        }
    };

    // fragment read offsets (elems): row*64 + (g ^ (l16&7))*8, g = kk*4+quad
    const int swz = l16 & 7;
    const int arow = (wm * 128 + l16) * 64;            // + mi*1024
    const int brow = 16384 + (wn * 64 + l16) * 64;     // + ni*1024
    const int cb0 = (quad ^ swz) * 8;                  // kk = 0
    const int cb1 = ((4 + quad) ^ swz) * 8;            // kk = 1

    f32x4 acc[8][4];
#pragma unroll
    for (int mi = 0; mi < 8; ++mi)
#pragma unroll
        for (int ni = 0; ni < 4; ++ni) acc[mi][ni] = {0.f, 0.f, 0.f, 0.f};

    // prologue: stage tile0 -> buf0, drain, barrier
    GSTAGE(0);
    asm volatile("s_waitcnt vmcnt(0)\n\ts_barrier" ::: "memory");

    for (int tt = 0; tt < NT; ++tt) {
        const unsigned short* Lb = &lds[(tt & 1) * 32768];
        if (tt + 1 < NT) GSTAGE((tt + 1) & 1);   // lands during this compute
        bf16x8 af[8], bfr[4];
        // ---- kk = 0 half ----
#pragma unroll
        for (int mi = 0; mi < 8; ++mi)
            af[mi] = __builtin_bit_cast(bf16x8,
                *reinterpret_cast<const u16x8*>(&Lb[arow + mi * 1024 + cb0]));
#pragma unroll
        for (int ni = 0; ni < 4; ++ni)
            bfr[ni] = __builtin_bit_cast(bf16x8,
                *reinterpret_cast<const u16x8*>(&Lb[brow + ni * 1024 + cb0]));
        __builtin_amdgcn_s_setprio(1);
#pragma unroll
        for (int mi = 0; mi < 8; ++mi)
#pragma unroll
            for (int ni = 0; ni < 4; ++ni)
                acc[mi][ni] = __builtin_amdgcn_mfma_f32_16x16x32_bf16(
                    af[mi], bfr[ni], acc[mi][ni], 0, 0, 0);
        __builtin_amdgcn_s_setprio(0);
        // ---- kk = 1 half ----
#pragma unroll
        for (int mi = 0; mi < 8; ++mi)
            af[mi] = __builtin_bit_cast(bf16x8,
                *reinterpret_cast<const u16x8*>(&Lb[arow + mi * 1024 + cb1]));
#pragma unroll
        for (int ni = 0; ni < 4; ++ni)
            bfr[ni] = __builtin_bit_cast(bf16x8,
                *reinterpret_cast<const u16x8*>(&Lb[brow + ni * 1024 + cb1]));
        __builtin_amdgcn_s_setprio(1);
#pragma unroll
        for (int mi = 0; mi < 8; ++mi)
#pragma unroll
            for (int ni = 0; ni < 4; ++ni)
                acc[mi][ni] = __builtin_amdgcn_mfma_f32_16x16x32_bf16(
                    af[mi], bfr[ni], acc[mi][ni], 0, 0, 0);
        __builtin_amdgcn_s_setprio(0);
        // ---- boundary: own staging loads long since landed ----
        if (tt + 1 < NT)
            asm volatile("s_waitcnt vmcnt(0)\n\ts_barrier" ::: "memory");
    }

#pragma unroll
    for (int mi = 0; mi < 8; ++mi) {
        const int gr0 = m0 + wm * 128 + mi * 16 + quad * 4;
#pragma unroll
        for (int ni = 0; ni < 4; ++ni) {
            const int gc = n0 + wn * 64 + ni * 16 + l16;
            if (MODE == 2) {
                const float bv = bias[gc];
                if (gc < 2048) {
#pragma unroll
                    for (int r = 0; r < 4; ++r)
                        ((unsigned short*)Cv)[(size_t)(gr0 + r) * 2048 + gc] =
                            f2b(acc[mi][ni][r] + bv);
                } else {
                    u16x4 pk;
#pragma unroll
                    for (int r = 0; r < 4; ++r) pk[r] = f2b(acc[mi][ni][r] + bv);
                    const int bb = gr0 >> 11, s0 = gr0 & 2047;
                    *reinterpret_cast<u16x4*>(
                        &((unsigned short*)Cv2)[((size_t)bb * 1024 + (gc - 2048)) * 2048 + s0]) = pk;
                }
            } else if (MODE == 5) {
                unsigned short* base = (blockIdx.z < 2)
                    ? (unsigned short*)Cv  + (size_t)blockIdx.z * 4096 * N
                    : (unsigned short*)Cv2 + (size_t)(blockIdx.z - 2) * 4096 * N;
#pragma unroll
                for (int r = 0; r < 4; ++r)
                    base[(size_t)(gr0 + r) * N + gc] = f2b(acc[mi][ni][r]);
            } else {
                const float bv = bias[gc];
#pragma unroll
                for (int r = 0; r < 4; ++r) {
                    float v = acc[mi][ni][r] + bv;
                    if (RELU) v = fmaxf(v, 0.f);
                    ((unsigned short*)Cv)[(size_t)(gr0 + r) * N + gc] = f2b(v);
                }
            }
        }
    }
}

// ---------------------------------------------------------------------------
// Flash attention, r13 (kept). K pre-scaled by log2(e)/8 -> p = exp2(s).
// qkb: [4096][2048] (Q 0..1023, K' 1024..2047, head h at h*64).
// vbT: [2][1024][2048]. Grid (16, 32): 128 q/block, 4 waves x 32 q.
// DMA staging into TRIPLE-buffered swizzled LDS, counted vmcnt(4), one
// barrier per tile. S^T via mfma(A=K, B=Q); PV A-frag via permlane swaps.
// ---------------------------------------------------------------------------
__global__ __launch_bounds__(256, 2) void attn_kernel(
    const unsigned short* __restrict__ qkb, const unsigned short* __restrict__ vbT,
    unsigned short* __restrict__ ao)
{
    __shared__ unsigned short lds[3 * 8192];   // [buf][K 4096 | V 4096] elems
    const int t = threadIdx.x;
    const int lane = t & 63;
    const int quad = lane >> 4, l16 = lane & 15;
    const int wave = t >> 6;
    const int bh = blockIdx.y;
    const int b = bh >> 4, h = bh & 15;
    const int q0 = blockIdx.x * 128 + wave * 32;
    const size_t qk_base = (size_t)b * 2048 * 2048;
    const size_t vt_base = (size_t)b * 1024 * 2048 + (size_t)h * 64 * 2048;

    // Q as B-operand: lane holds Q[q=l16 (+16m)][d=quad*8+j (+32kk)]
    bf16x8 qf[2][2];
#pragma unroll
    for (int m = 0; m < 2; ++m)
#pragma unroll
        for (int kk = 0; kk < 2; ++kk)
            qf[m][kk] = __builtin_bit_cast(bf16x8, *reinterpret_cast<const u16x8*>(
                &qkb[qk_base + (size_t)(q0 + m * 16 + l16) * 2048 + h * 64 + kk * 32 + quad * 8]));

    // ones fragment (bf16 1.0 = 0x3F80) for l = P @ 1
    u16x8 ones_u;
#pragma unroll
    for (int j = 0; j < 8; ++j) ones_u[j] = 0x3F80;
    const bf16x8 onesf = __builtin_bit_cast(bf16x8, ones_u);

    f32x4 o_acc[2][4], l_frag[2];
#pragma unroll
    for (int m = 0; m < 2; ++m) {
        l_frag[m] = {0.f, 0.f, 0.f, 0.f};
#pragma unroll
        for (int nf = 0; nf < 4; ++nf) o_acc[m][nf] = {0.f, 0.f, 0.f, 0.f};
    }

    // staging: chunk c (c0=t, c1=t+256): row=c>>3, src colblk=(c&7)^(row&7)
    const int c0 = t, c1 = t + 256;
    const int r0 = c0 >> 3, r1 = c1 >> 3;
    const int scb0 = (c0 & 7) ^ (r0 & 7), scb1 = (c1 & 7) ^ (r1 & 7);
    const unsigned short* kS0 = &qkb[qk_base + (size_t)r0 * 2048 + 1024 + h * 64 + scb0 * 8];
    const unsigned short* kS1 = &qkb[qk_base + (size_t)r1 * 2048 + 1024 + h * 64 + scb1 * 8];
    const unsigned short* vS0 = &vbT[vt_base + (size_t)r0 * 2048 + scb0 * 8];
    const unsigned short* vS1 = &vbT[vt_base + (size_t)r1 * 2048 + scb1 * 8];

    // fragment read base: row l16, swizzled colblk (quad ^ (l16&7))
    const int off0 = l16 * 64 + ((quad ^ (l16 & 7)) * 8);

#define STAGE(tile, buf)                                                      \
    {                                                                         \
        const size_t ko = (size_t)(tile) * 64 * 2048;                         \
        const int vo = (tile) * 64;                                           \
        async_cp16(kS0 + ko, &lds[(buf) * 8192 + c0 * 8]);                    \
        async_cp16(kS1 + ko, &lds[(buf) * 8192 + c1 * 8]);                    \
        async_cp16(vS0 + vo, &lds[(buf) * 8192 + 4096 + c0 * 8]);             \
        async_cp16(vS1 + vo, &lds[(buf) * 8192 + 4096 + c1 * 8]);             \
    }

    // prologue: tile0 -> buf0, tile1 -> buf1; wait tile0 (4 still in flight)
    STAGE(0, 0);
    STAGE(1, 1);
    asm volatile("s_waitcnt vmcnt(4)\n\ts_barrier" ::: "memory");

    for (int tt = 0; tt < 32; ++tt) {
        const int buf = tt - (tt / 3) * 3;
        const int pf = tt + 2;
        if (pf < 32) {
            const int bp = pf - (pf / 3) * 3;
            STAGE(pf, bp);
        }
        const unsigned short* LK = &lds[buf * 8192];
        const unsigned short* LV = LK + 4096;

        // S^T for the four 16-key fragments of this 64-key tile
        unsigned d0[2][4], d1[2][4];   // [m][kf]
#pragma unroll
        for (int kf = 0; kf < 4; ++kf) {
            bf16x8 kfr0 = __builtin_bit_cast(bf16x8,
                *reinterpret_cast<const u16x8*>(&LK[off0 + kf * 1024]));
            bf16x8 kfr1 = __builtin_bit_cast(bf16x8,
                *reinterpret_cast<const u16x8*>(&LK[(off0 ^ 32) + kf * 1024]));
#pragma unroll
            for (int m = 0; m < 2; ++m) {
                f32x4 s = {0.f, 0.f, 0.f, 0.f};
                s = __builtin_amdgcn_mfma_f32_16x16x32_bf16(kfr0, qf[m][0], s, 0, 0, 0);
                s = __builtin_amdgcn_mfma_f32_16x16x32_bf16(kfr1, qf[m][1], s, 0, 0, 0);
                d0[m][kf] = (unsigned)f2b(exp2f(s[0])) |
                            ((unsigned)f2b(exp2f(s[1])) << 16);
                d1[m][kf] = (unsigned)f2b(exp2f(s[2])) |
                            ((unsigned)f2b(exp2f(s[3])) << 16);
            }
        }
#pragma unroll
        for (int kh = 0; kh < 2; ++kh) {
            bf16x8 pfr[2];
#pragma unroll
            for (int m = 0; m < 2; ++m) {
                unsigned x0 = d0[m][kh * 2], y0 = d0[m][kh * 2 + 1];
                unsigned x1 = d1[m][kh * 2], y1 = d1[m][kh * 2 + 1];
                asm("v_permlane32_swap_b32 %0, %1\n\t"
                    "v_permlane16_swap_b32 %0, %1"
                    : "+v"(x0), "+v"(y0));
                asm("v_permlane32_swap_b32 %0, %1\n\t"
                    "v_permlane16_swap_b32 %0, %1"
                    : "+v"(x1), "+v"(y1));
                u32x4 pw = {x0, x1, y0, y1};   // W0,W1,W2,W3
                pfr[m] = __builtin_bit_cast(bf16x8, pw);
                l_frag[m] = __builtin_amdgcn_mfma_f32_16x16x32_bf16(
                    pfr[m], onesf, l_frag[m], 0, 0, 0);
            }
            __builtin_amdgcn_s_setprio(1);
#pragma unroll
            for (int nf = 0; nf < 4; ++nf) {
                bf16x8 vfr = __builtin_bit_cast(bf16x8,
                    *reinterpret_cast<const u16x8*>(&LV[(off0 ^ (kh * 32)) + nf * 1024]));
#pragma unroll
                for (int m = 0; m < 2; ++m)
                    o_acc[m][nf] = __builtin_amdgcn_mfma_f32_16x16x32_bf16(
                        pfr[m], vfr, o_acc[m][nf], 0, 0, 0);
            }
            __builtin_amdgcn_s_setprio(0);
        }
        // boundary: tile tt+1 visible after barrier; tile tt+2 still in flight
        if (tt + 1 < 32) {
            if (pf < 32)
                asm volatile("s_waitcnt vmcnt(4)\n\ts_barrier" ::: "memory");
            else
                asm volatile("s_waitcnt vmcnt(0)\n\ts_barrier" ::: "memory");
        }
    }
#undef STAGE

    // store: o_acc rows q = q0 + m*16 + quad*4 + r; l_frag rows align.
#pragma unroll
    for (int m = 0; m < 2; ++m) {
#pragma unroll
        for (int r = 0; r < 4; ++r) {
            const float inv = 1.0f / l_frag[m][r];
            const int row = q0 + m * 16 + quad * 4 + r;
#pragma unroll
            for (int nf = 0; nf < 4; ++nf)
                ao[(size_t)b * 2048 * 1024 + (size_t)row * 1024 + h * 64 + nf * 16 + l16] =
                    f2b(o_acc[m][nf][r] * inv);
        }
    }
}

// ---------------------------------------------------------------------------
extern "C" void kernel_launch(void* const* d_in, const int* in_sizes, int n_in,
                              void* d_out, int out_size, void* d_ws, size_t ws_size,
                              hipStream_t stream)
{
    const float* x   = (const float*)d_in[0];
    const float* wq  = (const float*)d_in[1];
    const float* bq  = (const float*)d_in[2];
    const float* wk  = (const float*)d_in[3];
    const float* bk  = (const float*)d_in[4];
    const float* wv  = (const float*)d_in[5];
    const float* bv  = (const float*)d_in[6];
    const float* wo  = (const float*)d_in[7];
    const float* bo  = (const float*)d_in[8];
    const float* w1  = (const float*)d_in[9];
    const float* b1  = (const float*)d_in[10];
    const float* w2  = (const float*)d_in[11];
    const float* b2  = (const float*)d_in[12];
    const float* g1  = (const float*)d_in[13];
    const float* be1 = (const float*)d_in[14];
    const float* g2  = (const float*)d_in[15];
    const float* be2 = (const float*)d_in[16];
    float* out = (float*)d_out;
    char*  ws  = (char*)d_ws;

    const int M = 4096, D = 1024, DFF = 4096;
    const size_t MB = 1 << 20;

    unsigned short* wqkvT = (unsigned short*)(ws + 0 * MB);   // [3072][1024] 6MB
    unsigned short* woT   = (unsigned short*)(ws + 6 * MB);   // 2MB
    unsigned short* w1T   = (unsigned short*)(ws + 8 * MB);   // 8MB
    unsigned short* w2T   = (unsigned short*)(ws + 16 * MB);  // 8MB
    unsigned short* ln    = (unsigned short*)(ws + 24 * MB);  // 8MB
    unsigned short* qkb   = (unsigned short*)(ws + 32 * MB);  // 16MB
    unsigned short* vbT   = (unsigned short*)(ws + 48 * MB);  // 8MB
    unsigned short* ao    = (unsigned short*)(ws + 56 * MB);  // 8MB
    unsigned short* ff1   = (unsigned short*)(ws + 32 * MB);  // 32MB (reuse)
    float*          x2    = (float*)(ws + 64 * MB);           // 16MB
    float*          bqkv  = (float*)(ws + 80 * MB);           // 12KB (pre-partials)
    unsigned short* pHi   = (unsigned short*)(ws + 80 * MB);  // slices 0,1 (16MB)
    unsigned short* pOlo  = (unsigned short*)(ws + 32 * MB);  // O-proj slices 2,3
    unsigned short* pFlo  = (unsigned short*)(ws + 0 * MB);   // FF2 slices 2,3

    // --- weight prep + LN1 ---
    transpose_all_k<<<12288, 256, 0, stream>>>(wq, wk, wv, wo, w1, w2,
                                               wqkvT, woT, w1T, w2T);
    concat3_k<<<12, 256, 0, stream>>>(bq, bk, bv, bqkv);
    ln_kernel<<<M, 256, 0, stream>>>(x, g1, be1, ln);
    // --- fused QKV projection: QK' -> qkb, V -> vbT (V^T) ---
    gemm256<2, 0><<<dim3(12, 16), 512, 0, stream>>>(
        ln, D, wqkvT, D, bqkv, qkb, vbT, 3072, D);
    // --- attention ---
    attn_kernel<<<dim3(16, 32), 256, 0, stream>>>(qkb, vbT, ao);
    // --- O projection split-K4 bf16 partials; reduce + residual + LN2 ---
    gemm256<5, 0><<<dim3(4, 16, 4), 512, 0, stream>>>(
        ao, D, woT, D, nullptr, pHi, pOlo, 1024, 256);
    reduce_ln_kernel<<<M, 256, 0, stream>>>(pHi, pOlo, bo, x, g2, be2, x2, ln);
    // --- FFN ---
    gemm256<0, 1><<<dim3(16, 16), 512, 0, stream>>>(
        ln, D, w1T, D, b1, ff1, nullptr, DFF, D);
    gemm256<5, 0><<<dim3(4, 16, 4), 512, 0, stream>>>(
        ff1, DFF, w2T, DFF, nullptr, pHi, pFlo, 1024, 1024);
    reduce_out4_k<<<4096, 256, 0, stream>>>(pHi, pFlo, b2, x2, out);
}